// Round 4
// baseline (3226.556 us; speedup 1.0000x reference)
//
#include <hip/hip_runtime.h>

#define BM 64
#define NTHREADS 512   // atom_pre / legacy
#define NT2 1024       // fused3: 16 waves

typedef __attribute__((ext_vector_type(8))) short short8;
typedef __attribute__((ext_vector_type(4))) float f32x4;

__device__ __forceinline__ short f2bf(float f) {
  unsigned u = __builtin_bit_cast(unsigned, f);
  u += 0x7FFFu + ((u >> 16) & 1u);   // RNE
  return (short)(u >> 16);
}
__device__ __forceinline__ float bf2f(short s) {
  unsigned u = ((unsigned)(unsigned short)s) << 16;
  return __builtin_bit_cast(float, u);
}
__device__ __forceinline__ float elu_f(float v) {
  return v > 0.f ? v : (__expf(v) - 1.f);
}

// ---- pack f32 [K][N] weight into bf16 MFMA-fragment order ----
__global__ __launch_bounds__(256) void pack_w(const float* __restrict__ src,
                                              short* __restrict__ dst,
                                              int K, int N, int rev) {
  int tile = blockIdx.x * 4 + (threadIdx.x >> 6);
  int lane = threadIdx.x & 63;
  int ktiles = K >> 5;
  int tot = (N >> 4) * ktiles;
  if (tile >= tot) return;
  int nt = tile / ktiles, kt = tile - nt * ktiles;
  int col = (nt << 4) + (lane & 15);
  int k0 = (kt << 5) + ((lane >> 4) << 3);
  short8 o;
#pragma unroll
  for (int j = 0; j < 8; ++j) {
    int kr = k0 + j;
    if (rev) kr = ((3 - (kr >> 8)) << 8) | (kr & 255);
    o[j] = f2bf(src[(size_t)kr * N + col]);
  }
  *(short8*)(dst + (size_t)tile * 512 + lane * 8) = o;
}

__device__ __forceinline__ short8 lds_afrag(const char* base, int stride, int rt,
                                            int kt, int lane) {
  int row = rt * 16 + (lane & 15);
  int boff = (kt << 6) + ((lane >> 4) << 4);
  return *(const short8*)(base + row * stride + (boff ^ ((row & 7) << 4)));
}
__device__ __forceinline__ short8 ldg_bfrag(const short* W, int ktiles, int ct,
                                            int kt, int lane) {
  return *(const short8*)(W + ((size_t)(ct * ktiles + kt) << 9) + (lane << 3));
}

// ================= atom precompute =================
// p[a][s][c] = h_a(256) @ Ws0[256s:256s+256, :]   (bf16, [n_atoms][4][512])
__global__ __launch_bounds__(NTHREADS) void atom_pre(const float* __restrict__ h,
                                                     const short* __restrict__ W0f,
                                                     short* __restrict__ p,
                                                     int n_atoms) {
  __shared__ char sh[BM * 512];
  const int tid = threadIdx.x, lane = tid & 63, wv = tid >> 6;
  const int r0 = blockIdx.x * BM;
  for (int i = tid; i < BM * 32; i += NTHREADS) {
    int row = i >> 5, c0 = (i & 31) << 3;
    int ga = r0 + row;
    short8 o;
    if (ga < n_atoms) {
      const float4* s4 = (const float4*)(h + (size_t)ga * 256 + c0);
      float4 v0 = s4[0], v1 = s4[1];
      o[0] = f2bf(v0.x); o[1] = f2bf(v0.y); o[2] = f2bf(v0.z); o[3] = f2bf(v0.w);
      o[4] = f2bf(v1.x); o[5] = f2bf(v1.y); o[6] = f2bf(v1.z); o[7] = f2bf(v1.w);
    } else {
#pragma unroll
      for (int e = 0; e < 8; ++e) o[e] = 0;
    }
    *(short8*)(sh + row * 512 + ((c0 * 2) ^ ((row & 7) << 4))) = o;
  }
  __syncthreads();
#pragma unroll 1
  for (int s = 0; s < 4; ++s) {
    f32x4 acc[4][4];
    const f32x4 z = {0.f, 0.f, 0.f, 0.f};
#pragma unroll
    for (int rt = 0; rt < 4; ++rt)
#pragma unroll
      for (int cf = 0; cf < 4; ++cf) acc[rt][cf] = z;
    for (int kt = 0; kt < 8; ++kt) {
      short8 a[4], b[4];
#pragma unroll
      for (int rt = 0; rt < 4; ++rt) a[rt] = lds_afrag(sh, 512, rt, kt, lane);
#pragma unroll
      for (int cf = 0; cf < 4; ++cf)
        b[cf] = ldg_bfrag(W0f, 32, (wv << 2) + cf, (s << 3) + kt, lane);
#pragma unroll
      for (int rt = 0; rt < 4; ++rt)
#pragma unroll
        for (int cf = 0; cf < 4; ++cf)
          acc[rt][cf] = __builtin_amdgcn_mfma_f32_16x16x32_bf16(a[rt], b[cf], acc[rt][cf], 0, 0, 0);
    }
#pragma unroll
    for (int rt = 0; rt < 4; ++rt)
#pragma unroll
      for (int cf = 0; cf < 4; ++cf) {
        int col = (wv << 6) + (cf << 4) + (lane & 15);
#pragma unroll
        for (int i = 0; i < 4; ++i) {
          int row = rt * 16 + ((lane >> 4) << 2) + i;
          int ga = r0 + row;
          if (ga < n_atoms) p[((size_t)ga * 4 + s) * 512 + col] = f2bf(acc[rt][cf][i]);
        }
      }
  }
}

struct P2 {
  const int* idxs;
  const short* p;
  const short *W1, *W2, *W3, *Wt0, *Wt1, *Wc0;
  const float *bs0, *bs1, *bs2, *bs3, *bt0, *bt1, *bt2, *bc0, *bc1;
  const float *Wt2, *Wc1;
  float* out;
  int n_tors;
};

// ---- phase primitives (16 waves, wave owns cols wv*32..wv*32+31 = 2 cf) ----
// MFMA K-loop: acc = bias + src @ W   (bias folded into acc init)
__device__ __forceinline__ void phase_mfma(const char* src, const short* __restrict__ W,
                                           const float* __restrict__ bias,
                                           f32x4 (&acc)[4][2], int wv, int lane) {
  float b0 = bias[(wv << 5) + (lane & 15)];
  float b1 = bias[(wv << 5) + 16 + (lane & 15)];
#pragma unroll
  for (int rt = 0; rt < 4; ++rt) {
    acc[rt][0] = (f32x4){b0, b0, b0, b0};
    acc[rt][1] = (f32x4){b1, b1, b1, b1};
  }
  short8 bC[2], bN[2];
#pragma unroll
  for (int cf = 0; cf < 2; ++cf) bC[cf] = ldg_bfrag(W, 16, (wv << 1) + cf, 0, lane);
#pragma unroll 1
  for (int kt = 0; kt < 16; ++kt) {
#pragma unroll
    for (int cf = 0; cf < 2; ++cf)
      bN[cf] = ldg_bfrag(W, 16, (wv << 1) + cf, (kt + 1) & 15, lane);
    short8 a[4];
#pragma unroll
    for (int rt = 0; rt < 4; ++rt) a[rt] = lds_afrag(src, 1024, rt, kt, lane);
#pragma unroll
    for (int rt = 0; rt < 4; ++rt)
#pragma unroll
      for (int cf = 0; cf < 2; ++cf)
        acc[rt][cf] = __builtin_amdgcn_mfma_f32_16x16x32_bf16(a[rt], bC[cf], acc[rt][cf], 0, 0, 0);
#pragma unroll
    for (int cf = 0; cf < 2; ++cf) bC[cf] = bN[cf];
  }
}

// epilogue: dst = elu(acc) + res [+ extra]   (per-thread owned elements only)
template <bool EXTRA>
__device__ __forceinline__ void epi_phase(char* dst, const char* res, const char* extra,
                                          const f32x4 (&acc)[4][2], int wv, int lane) {
#pragma unroll
  for (int rt = 0; rt < 4; ++rt)
#pragma unroll
    for (int cf = 0; cf < 2; ++cf) {
      int col = (wv << 5) + (cf << 4) + (lane & 15);
#pragma unroll
      for (int i = 0; i < 4; ++i) {
        int row = rt * 16 + ((lane >> 4) << 2) + i;
        size_t off = (size_t)row * 1024 + ((col * 2) ^ ((row & 7) << 4));
        float v = elu_f(acc[rt][cf][i]) + bf2f(*(const short*)(res + off));
        if (EXTRA) v += bf2f(*(const short*)(extra + off));
        *(short*)(dst + off) = f2bf(v);
      }
    }
}

// Phase pipeline:
//  G | f1 | ef1+r1 | er1+f2 | ef2+r2 | er2+f3 | ef3+r3 | er3->sym(sB) | t0 |
//  et0(sA)+c | ec(sB)+t1 | et1(sA) | proj
__global__ __launch_bounds__(NT2) void fused3(P2 p) {
  __shared__ char smem[BM * 2048];     // sA | sB (64 KB each)
  __shared__ int sIdx[BM * 4];
  __shared__ float sSmall[BM * 12];
  char* sA = smem;
  char* sB = smem + BM * 1024;
  const int tid = threadIdx.x;
  const int lane = tid & 63;
  const int wv = tid >> 6;             // 0..15
  const int r0 = blockIdx.x * BM;

  for (int i = tid; i < BM * 4; i += NT2) {
    int grow = r0 + (i >> 2);
    sIdx[i] = (grow < p.n_tors) ? p.idxs[(size_t)grow * 4 + (i & 3)] : 0;
  }
  __syncthreads();

  // ---- G: layer0 via gathered per-atom partials -> sA (fwd), sB (rev) ----
  for (int i = tid; i < BM * 64; i += NT2) {
    int row = i >> 6, c0 = (i & 63) << 3;
    float sf[8], sr[8];
#pragma unroll
    for (int e = 0; e < 8; ++e) { sf[e] = p.bs0[c0 + e]; sr[e] = sf[e]; }
#pragma unroll
    for (int j = 0; j < 4; ++j) {
      int a = sIdx[row * 4 + j];
      short8 vf = *(const short8*)(p.p + ((size_t)a * 4 + j) * 512 + c0);
      short8 vr = *(const short8*)(p.p + ((size_t)a * 4 + (3 - j)) * 512 + c0);
#pragma unroll
      for (int e = 0; e < 8; ++e) { sf[e] += bf2f(vf[e]); sr[e] += bf2f(vr[e]); }
    }
    short8 of, orv;
#pragma unroll
    for (int e = 0; e < 8; ++e) { of[e] = f2bf(elu_f(sf[e])); orv[e] = f2bf(elu_f(sr[e])); }
    size_t off = (size_t)row * 1024 + ((c0 * 2) ^ ((row & 7) << 4));
    *(short8*)(sA + off) = of;
    *(short8*)(sB + off) = orv;
  }
  __syncthreads();

  f32x4 accA[4][2], accB[4][2];

  // ph1: f1
  phase_mfma(sA, p.W1, p.bs1, accA, wv, lane);
  __syncthreads();
  // ph2: ef1 -> sA  ||  r1 (reads sB)
  epi_phase<false>(sA, sA, nullptr, accA, wv, lane);
  phase_mfma(sB, p.W1, p.bs1, accB, wv, lane);
  __syncthreads();
  // ph3: er1 -> sB  ||  f2 (reads sA)
  epi_phase<false>(sB, sB, nullptr, accB, wv, lane);
  phase_mfma(sA, p.W2, p.bs2, accA, wv, lane);
  __syncthreads();
  // ph4: ef2 -> sA  ||  r2 (reads sB)
  epi_phase<false>(sA, sA, nullptr, accA, wv, lane);
  phase_mfma(sB, p.W2, p.bs2, accB, wv, lane);
  __syncthreads();
  // ph5: er2 -> sB  ||  f3 (reads sA)
  epi_phase<false>(sB, sB, nullptr, accB, wv, lane);
  phase_mfma(sA, p.W3, p.bs3, accA, wv, lane);
  __syncthreads();
  // ph6: ef3 -> sA  ||  r3 (reads sB)
  epi_phase<false>(sA, sA, nullptr, accA, wv, lane);
  phase_mfma(sB, p.W3, p.bs3, accB, wv, lane);
  __syncthreads();
  // ph7: er3 + sym:  sB = elu(accB) + sB(r-res) + sA(f3)   (VALU-only phase)
  epi_phase<true>(sB, sB, sA, accB, wv, lane);
  __syncthreads();
  // ph8: t0 = MFMA(sym=sB, Wt0)
  phase_mfma(sB, p.Wt0, p.bt0, accA, wv, lane);
  __syncthreads();
  // ph9: et0 -> sA (res = sym sB)  ||  c-MFMA (reads sB)
  epi_phase<false>(sA, sB, nullptr, accA, wv, lane);
  phase_mfma(sB, p.Wc0, p.bc0, accB, wv, lane);
  __syncthreads();
  // ph10: ec -> sB (res = sym sB, own-el read-then-write)  ||  t1-MFMA (reads sA=t0)
  epi_phase<false>(sB, sB, nullptr, accB, wv, lane);
  phase_mfma(sA, p.Wt1, p.bt1, accA, wv, lane);
  __syncthreads();
  // ph11: et1 -> sA (res = t0 sA)
  epi_phase<false>(sA, sA, nullptr, accA, wv, lane);
  __syncthreads();

  // ---- proj: t1 in sA, c in sB ----
  for (int idx = tid; idx < BM * 12; idx += NT2) {
    int row = idx / 12, jj = idx - row * 12;
    int j = (jj < 6) ? jj : jj - 6;
    const char* src = (jj < 6) ? sA : sB;
    const float* W = (jj < 6) ? p.Wt2 : p.Wc1;
    float acc = (jj < 6) ? p.bt2[j] : p.bc1[j];
    for (int c0 = 0; c0 < 512; c0 += 8) {
      short8 v = *(const short8*)(src + (size_t)row * 1024 + ((c0 * 2) ^ ((row & 7) << 4)));
#pragma unroll
      for (int e = 0; e < 8; ++e) acc += bf2f(v[e]) * W[(c0 + e) * 6 + j];
    }
    sSmall[row * 12 + jj] = acc;
  }
  __syncthreads();
  for (int idx = tid; idx < BM * 6; idx += NT2) {
    int row = idx / 6, j = idx - row * 6;
    int grow = r0 + row;
    if (grow < p.n_tors) {
      float score = sSmall[row * 12 + 6 + j];
      float coeff = sSmall[row * 12 + j];
      p.out[(size_t)grow * 6 + j] = score;
      p.out[(size_t)p.n_tors * 6 + (size_t)grow * 6 + j] =
          coeff * 0.001f * (1.0f / (1.0f + __expf(-score)));
    }
  }
}

// ================= LEGACY PATH (fallback if ws too small) =================

struct Params {
  const float* h;
  const int* idxs;
  const short *W0f, *W0r, *W1, *W2, *W3, *Wt0, *Wt1, *Wc0;
  const float *bs0, *bs1, *bs2, *bs3, *bt0, *bt1, *bt2, *bc0, *bc1;
  const float *Wt2, *Wc1;
  float* out;
  int n_tors;
};

__device__ __forceinline__ void layer_dual(char* hf, char* hr,
                                           const short* __restrict__ W,
                                           const float* __restrict__ bias,
                                           int wv, int lane) {
  f32x4 accf[4][4], accr[4][4];
  const f32x4 z = {0.f, 0.f, 0.f, 0.f};
#pragma unroll
  for (int rt = 0; rt < 4; ++rt)
#pragma unroll
    for (int cf = 0; cf < 4; ++cf) { accf[rt][cf] = z; accr[rt][cf] = z; }
  for (int kt = 0; kt < 16; ++kt) {
    short8 af[4], ar[4], b[4];
#pragma unroll
    for (int rt = 0; rt < 4; ++rt) {
      af[rt] = lds_afrag(hf, 1024, rt, kt, lane);
      ar[rt] = lds_afrag(hr, 1024, rt, kt, lane);
    }
#pragma unroll
    for (int cf = 0; cf < 4; ++cf) b[cf] = ldg_bfrag(W, 16, (wv << 2) + cf, kt, lane);
#pragma unroll
    for (int rt = 0; rt < 4; ++rt)
#pragma unroll
      for (int cf = 0; cf < 4; ++cf) {
        accf[rt][cf] = __builtin_amdgcn_mfma_f32_16x16x32_bf16(af[rt], b[cf], accf[rt][cf], 0, 0, 0);
        accr[rt][cf] = __builtin_amdgcn_mfma_f32_16x16x32_bf16(ar[rt], b[cf], accr[rt][cf], 0, 0, 0);
      }
  }
  float bcol[4];
#pragma unroll
  for (int cf = 0; cf < 4; ++cf) bcol[cf] = bias[(wv << 6) + (cf << 4) + (lane & 15)];
  __syncthreads();
#pragma unroll
  for (int rt = 0; rt < 4; ++rt)
#pragma unroll
    for (int cf = 0; cf < 4; ++cf) {
      int col = (wv << 6) + (cf << 4) + (lane & 15);
#pragma unroll
      for (int i = 0; i < 4; ++i) {
        int row = rt * 16 + ((lane >> 4) << 2) + i;
        size_t off = (size_t)row * 1024 + ((col * 2) ^ ((row & 7) << 4));
        short* pf = (short*)(hf + off);
        short* pr = (short*)(hr + off);
        *pf = f2bf(bf2f(*pf) + elu_f(accf[rt][cf][i] + bcol[cf]));
        *pr = f2bf(bf2f(*pr) + elu_f(accr[rt][cf][i] + bcol[cf]));
      }
    }
  __syncthreads();
}

__device__ __forceinline__ void layer_single(const char* in,
                                             const short* __restrict__ W,
                                             const float* __restrict__ bias,
                                             const char* res, char* out,
                                             int wv, int lane) {
  f32x4 acc[4][4];
  const f32x4 z = {0.f, 0.f, 0.f, 0.f};
#pragma unroll
  for (int rt = 0; rt < 4; ++rt)
#pragma unroll
    for (int cf = 0; cf < 4; ++cf) acc[rt][cf] = z;
  for (int kt = 0; kt < 16; ++kt) {
    short8 a[4], b[4];
#pragma unroll
    for (int rt = 0; rt < 4; ++rt) a[rt] = lds_afrag(in, 1024, rt, kt, lane);
#pragma unroll
    for (int cf = 0; cf < 4; ++cf) b[cf] = ldg_bfrag(W, 16, (wv << 2) + cf, kt, lane);
#pragma unroll
    for (int rt = 0; rt < 4; ++rt)
#pragma unroll
      for (int cf = 0; cf < 4; ++cf)
        acc[rt][cf] = __builtin_amdgcn_mfma_f32_16x16x32_bf16(a[rt], b[cf], acc[rt][cf], 0, 0, 0);
  }
  float bcol[4];
#pragma unroll
  for (int cf = 0; cf < 4; ++cf) bcol[cf] = bias[(wv << 6) + (cf << 4) + (lane & 15)];
  __syncthreads();
#pragma unroll
  for (int rt = 0; rt < 4; ++rt)
#pragma unroll
    for (int cf = 0; cf < 4; ++cf) {
      int col = (wv << 6) + (cf << 4) + (lane & 15);
#pragma unroll
      for (int i = 0; i < 4; ++i) {
        int row = rt * 16 + ((lane >> 4) << 2) + i;
        size_t off = (size_t)row * 1024 + ((col * 2) ^ ((row & 7) << 4));
        float v = elu_f(acc[rt][cf][i] + bcol[cf]) + bf2f(*(const short*)(res + off));
        *(short*)(out + off) = f2bf(v);
      }
    }
  __syncthreads();
}

__global__ __launch_bounds__(NTHREADS) void fused(Params p) {
  __shared__ char smem[BM * 2048];
  __shared__ float sSmall[BM * 12];
  char* sA = smem;
  char* sB = smem + BM * 1024;
  const int tid = threadIdx.x;
  const int lane = tid & 63;
  const int wv = tid >> 6;
  const int r0 = blockIdx.x * BM;

  for (int c = tid; c < BM * 128; c += NTHREADS) {
    int row = c >> 7;
    int col0 = (c & 127) << 3;
    int grow = r0 + row;
    short8 o;
    if (grow < p.n_tors) {
      int f = col0 >> 8;
      int cin = col0 & 255;
      int a = p.idxs[(size_t)grow * 4 + f];
      const float4* s4 = (const float4*)(p.h + (size_t)a * 256 + cin);
      float4 v0 = s4[0], v1 = s4[1];
      o[0] = f2bf(v0.x); o[1] = f2bf(v0.y); o[2] = f2bf(v0.z); o[3] = f2bf(v0.w);
      o[4] = f2bf(v1.x); o[5] = f2bf(v1.y); o[6] = f2bf(v1.z); o[7] = f2bf(v1.w);
    } else {
#pragma unroll
      for (int e = 0; e < 8; ++e) o[e] = 0;
    }
    *(short8*)(smem + (size_t)row * 2048 + ((col0 * 2) ^ ((row & 7) << 4))) = o;
  }
  __syncthreads();

  {
    f32x4 accf[4][4], accr[4][4];
    const f32x4 z = {0.f, 0.f, 0.f, 0.f};
#pragma unroll
    for (int rt = 0; rt < 4; ++rt)
#pragma unroll
      for (int cf = 0; cf < 4; ++cf) { accf[rt][cf] = z; accr[rt][cf] = z; }
    for (int kt = 0; kt < 32; ++kt) {
      short8 a[4], bfw[4], brw[4];
#pragma unroll
      for (int rt = 0; rt < 4; ++rt) a[rt] = lds_afrag(smem, 2048, rt, kt, lane);
#pragma unroll
      for (int cf = 0; cf < 4; ++cf) {
        bfw[cf] = ldg_bfrag(p.W0f, 32, (wv << 2) + cf, kt, lane);
        brw[cf] = ldg_bfrag(p.W0r, 32, (wv << 2) + cf, kt, lane);
      }
#pragma unroll
      for (int rt = 0; rt < 4; ++rt)
#pragma unroll
        for (int cf = 0; cf < 4; ++cf) {
          accf[rt][cf] = __builtin_amdgcn_mfma_f32_16x16x32_bf16(a[rt], bfw[cf], accf[rt][cf], 0, 0, 0);
          accr[rt][cf] = __builtin_amdgcn_mfma_f32_16x16x32_bf16(a[rt], brw[cf], accr[rt][cf], 0, 0, 0);
        }
    }
    float bcol[4];
#pragma unroll
    for (int cf = 0; cf < 4; ++cf) bcol[cf] = p.bs0[(wv << 6) + (cf << 4) + (lane & 15)];
    __syncthreads();
#pragma unroll
    for (int rt = 0; rt < 4; ++rt)
#pragma unroll
      for (int cf = 0; cf < 4; ++cf) {
        int col = (wv << 6) + (cf << 4) + (lane & 15);
#pragma unroll
        for (int i = 0; i < 4; ++i) {
          int row = rt * 16 + ((lane >> 4) << 2) + i;
          size_t off = (size_t)row * 1024 + ((col * 2) ^ ((row & 7) << 4));
          *(short*)(sA + off) = f2bf(elu_f(accf[rt][cf][i] + bcol[cf]));
          *(short*)(sB + off) = f2bf(elu_f(accr[rt][cf][i] + bcol[cf]));
        }
      }
    __syncthreads();
  }

  layer_dual(sA, sB, p.W1, p.bs1, wv, lane);
  layer_dual(sA, sB, p.W2, p.bs2, wv, lane);
  layer_dual(sA, sB, p.W3, p.bs3, wv, lane);

  for (int c = tid; c < BM * 64; c += NTHREADS) {
    int row = c >> 6;
    int col0 = (c & 63) << 3;
    size_t off = (size_t)row * 1024 + ((col0 * 2) ^ ((row & 7) << 4));
    short8 xa = *(short8*)(sA + off);
    short8 xb = *(short8*)(sB + off);
    short8 o;
#pragma unroll
    for (int e = 0; e < 8; ++e) o[e] = f2bf(bf2f(xa[e]) + bf2f(xb[e]));
    *(short8*)(sA + off) = o;
  }
  __syncthreads();

  layer_single(sA, p.Wt0, p.bt0, sA, sB, wv, lane);
  layer_single(sB, p.Wt1, p.bt1, sB, sB, wv, lane);
  layer_single(sA, p.Wc0, p.bc0, sA, sA, wv, lane);

  for (int idx = tid; idx < BM * 12; idx += NTHREADS) {
    int row = idx / 12, jj = idx - row * 12;
    int j = (jj < 6) ? jj : jj - 6;
    const char* src = (jj < 6) ? sB : sA;
    const float* W = (jj < 6) ? p.Wt2 : p.Wc1;
    float acc = (jj < 6) ? p.bt2[j] : p.bc1[j];
    for (int c0 = 0; c0 < 512; c0 += 8) {
      short8 v = *(const short8*)(src + (size_t)row * 1024 + ((c0 * 2) ^ ((row & 7) << 4)));
#pragma unroll
      for (int e = 0; e < 8; ++e) acc += bf2f(v[e]) * W[(c0 + e) * 6 + j];
    }
    sSmall[row * 12 + jj] = acc;
  }
  __syncthreads();
  for (int idx = tid; idx < BM * 6; idx += NTHREADS) {
    int row = idx / 6, j = idx - row * 6;
    int grow = r0 + row;
    if (grow < p.n_tors) {
      float score = sSmall[row * 12 + 6 + j];
      float coeff = sSmall[row * 12 + j];
      p.out[(size_t)grow * 6 + j] = score;
      p.out[(size_t)p.n_tors * 6 + (size_t)grow * 6 + j] =
          coeff * 0.001f * (1.0f / (1.0f + __expf(-score)));
    }
  }
}

// ================= LAUNCH =================

extern "C" void kernel_launch(void* const* d_in, const int* in_sizes, int n_in,
                              void* d_out, int out_size, void* d_ws, size_t ws_size,
                              hipStream_t stream) {
  const float* h   = (const float*)d_in[0];
  const int* idxs  = (const int*)d_in[1];
  const float* Ws0 = (const float*)d_in[2];
  const float* bs0 = (const float*)d_in[3];
  const float* Ws1 = (const float*)d_in[4];
  const float* bs1 = (const float*)d_in[5];
  const float* Ws2 = (const float*)d_in[6];
  const float* bs2 = (const float*)d_in[7];
  const float* Ws3 = (const float*)d_in[8];
  const float* bs3 = (const float*)d_in[9];
  const float* Wt0 = (const float*)d_in[10];
  const float* bt0 = (const float*)d_in[11];
  const float* Wt1 = (const float*)d_in[12];
  const float* bt1 = (const float*)d_in[13];
  const float* Wt2 = (const float*)d_in[14];
  const float* bt2 = (const float*)d_in[15];
  const float* Wc0 = (const float*)d_in[16];
  const float* bc0 = (const float*)d_in[17];
  const float* Wc1 = (const float*)d_in[18];
  const float* bc1 = (const float*)d_in[19];
  int n_tors = in_sizes[1] / 4;
  int n_atoms = in_sizes[0] / 256;

  auto pk = [&](const float* s, short* dmem, int K, int N, int rev) {
    int tiles = (N >> 4) * (K >> 5);
    pack_w<<<dim3((tiles + 3) / 4), dim3(256), 0, stream>>>(s, dmem, K, N, rev);
  };

  size_t pElems = (size_t)n_atoms * 4 * 512;
  size_t needNew = (pElems + 524288 + 6 * 262144) * sizeof(short);

  if (ws_size >= needNew) {
    short* ws = (short*)d_ws;
    short* pT  = ws;
    short* W0f = ws + pElems;
    short* W1  = W0f + 524288;
    short* W2  = W1 + 262144;
    short* W3  = W2 + 262144;
    short* Wt0c = W3 + 262144;
    short* Wt1c = Wt0c + 262144;
    short* Wc0c = Wt1c + 262144;

    pk(Ws0, W0f, 1024, 512, 0);
    pk(Ws1, W1, 512, 512, 0);
    pk(Ws2, W2, 512, 512, 0);
    pk(Ws3, W3, 512, 512, 0);
    pk(Wt0, Wt0c, 512, 512, 0);
    pk(Wt1, Wt1c, 512, 512, 0);
    pk(Wc0, Wc0c, 512, 512, 0);

    atom_pre<<<dim3((n_atoms + BM - 1) / BM), dim3(NTHREADS), 0, stream>>>(h, W0f, pT, n_atoms);

    P2 p;
    p.idxs = idxs; p.p = pT;
    p.W1 = W1; p.W2 = W2; p.W3 = W3;
    p.Wt0 = Wt0c; p.Wt1 = Wt1c; p.Wc0 = Wc0c;
    p.bs0 = bs0; p.bs1 = bs1; p.bs2 = bs2; p.bs3 = bs3;
    p.bt0 = bt0; p.bt1 = bt1; p.bt2 = bt2; p.bc0 = bc0; p.bc1 = bc1;
    p.Wt2 = Wt2; p.Wc1 = Wc1;
    p.out = (float*)d_out; p.n_tors = n_tors;

    fused3<<<dim3((n_tors + BM - 1) / BM), dim3(NT2), 0, stream>>>(p);
  } else {
    short* ws = (short*)d_ws;
    short* W0f = ws;
    short* W0r = ws + 524288;
    short* W1  = ws + 1048576;
    short* W2  = W1 + 262144;
    short* W3  = W2 + 262144;
    short* Wt0c = W3 + 262144;
    short* Wt1c = Wt0c + 262144;
    short* Wc0c = Wt1c + 262144;

    pk(Ws0, W0f, 1024, 512, 0);
    pk(Ws0, W0r, 1024, 512, 1);
    pk(Ws1, W1, 512, 512, 0);
    pk(Ws2, W2, 512, 512, 0);
    pk(Ws3, W3, 512, 512, 0);
    pk(Wt0, Wt0c, 512, 512, 0);
    pk(Wt1, Wt1c, 512, 512, 0);
    pk(Wc0, Wc0c, 512, 512, 0);

    Params p;
    p.h = h; p.idxs = idxs;
    p.W0f = W0f; p.W0r = W0r; p.W1 = W1; p.W2 = W2; p.W3 = W3;
    p.Wt0 = Wt0c; p.Wt1 = Wt1c; p.Wc0 = Wc0c;
    p.bs0 = bs0; p.bs1 = bs1; p.bs2 = bs2; p.bs3 = bs3;
    p.bt0 = bt0; p.bt1 = bt1; p.bt2 = bt2; p.bc0 = bc0; p.bc1 = bc1;
    p.Wt2 = Wt2; p.Wc1 = Wc1;
    p.out = (float*)d_out; p.n_tors = n_tors;

    fused<<<dim3((n_tors + BM - 1) / BM), dim3(NTHREADS), 0, stream>>>(p);
  }
}

// Round 5
// 3065.334 us; speedup vs baseline: 1.0526x; 1.0526x over previous
//
#include <hip/hip_runtime.h>

#define BM 64
#define NTHREADS 512   // atom_pre / legacy
#define BM4 32
#define NT4 1024       // fused4: 16 waves, 2 blocks/CU

typedef __attribute__((ext_vector_type(8))) short short8;
typedef __attribute__((ext_vector_type(4))) float f32x4;

__device__ __forceinline__ short f2bf(float f) {
  unsigned u = __builtin_bit_cast(unsigned, f);
  u += 0x7FFFu + ((u >> 16) & 1u);   // RNE
  return (short)(u >> 16);
}
__device__ __forceinline__ float bf2f(short s) {
  unsigned u = ((unsigned)(unsigned short)s) << 16;
  return __builtin_bit_cast(float, u);
}
__device__ __forceinline__ float elu_f(float v) {
  return v > 0.f ? v : (__expf(v) - 1.f);
}

// ---- pack f32 [K][N] weight into bf16 MFMA-fragment order ----
__global__ __launch_bounds__(256) void pack_w(const float* __restrict__ src,
                                              short* __restrict__ dst,
                                              int K, int N, int rev) {
  int tile = blockIdx.x * 4 + (threadIdx.x >> 6);
  int lane = threadIdx.x & 63;
  int ktiles = K >> 5;
  int tot = (N >> 4) * ktiles;
  if (tile >= tot) return;
  int nt = tile / ktiles, kt = tile - nt * ktiles;
  int col = (nt << 4) + (lane & 15);
  int k0 = (kt << 5) + ((lane >> 4) << 3);
  short8 o;
#pragma unroll
  for (int j = 0; j < 8; ++j) {
    int kr = k0 + j;
    if (rev) kr = ((3 - (kr >> 8)) << 8) | (kr & 255);
    o[j] = f2bf(src[(size_t)kr * N + col]);
  }
  *(short8*)(dst + (size_t)tile * 512 + lane * 8) = o;
}

__device__ __forceinline__ short8 ldg_bfrag(const short* W, int ktiles, int ct,
                                            int kt, int lane) {
  return *(const short8*)(W + ((size_t)(ct * ktiles + kt) << 9) + (lane << 3));
}

// swizzled LDS byte offset for activation tiles: stride 1024 B/row
__device__ __forceinline__ int swz(int row, int boff) {
  return row * 1024 + (boff ^ ((row & 7) << 4) ^ (((row >> 3) & 1) << 7));
}
__device__ __forceinline__ short8 lds_a32(const char* base, int rt, int kt, int lane) {
  int row = rt * 16 + (lane & 15);
  int boff = (kt << 6) + ((lane >> 4) << 4);
  return *(const short8*)(base + swz(row, boff));
}

// ================= atom precompute (unchanged) =================
__device__ __forceinline__ short8 lds_afrag64(const char* base, int stride, int rt,
                                              int kt, int lane) {
  int row = rt * 16 + (lane & 15);
  int boff = (kt << 6) + ((lane >> 4) << 4);
  return *(const short8*)(base + row * stride + (boff ^ ((row & 7) << 4)));
}

__global__ __launch_bounds__(NTHREADS) void atom_pre(const float* __restrict__ h,
                                                     const short* __restrict__ W0f,
                                                     short* __restrict__ p,
                                                     int n_atoms) {
  __shared__ char sh[BM * 512];
  const int tid = threadIdx.x, lane = tid & 63, wv = tid >> 6;
  const int r0 = blockIdx.x * BM;
  for (int i = tid; i < BM * 32; i += NTHREADS) {
    int row = i >> 5, c0 = (i & 31) << 3;
    int ga = r0 + row;
    short8 o;
    if (ga < n_atoms) {
      const float4* s4 = (const float4*)(h + (size_t)ga * 256 + c0);
      float4 v0 = s4[0], v1 = s4[1];
      o[0] = f2bf(v0.x); o[1] = f2bf(v0.y); o[2] = f2bf(v0.z); o[3] = f2bf(v0.w);
      o[4] = f2bf(v1.x); o[5] = f2bf(v1.y); o[6] = f2bf(v1.z); o[7] = f2bf(v1.w);
    } else {
#pragma unroll
      for (int e = 0; e < 8; ++e) o[e] = 0;
    }
    *(short8*)(sh + row * 512 + ((c0 * 2) ^ ((row & 7) << 4))) = o;
  }
  __syncthreads();
#pragma unroll 1
  for (int s = 0; s < 4; ++s) {
    f32x4 acc[4][4];
    const f32x4 z = {0.f, 0.f, 0.f, 0.f};
#pragma unroll
    for (int rt = 0; rt < 4; ++rt)
#pragma unroll
      for (int cf = 0; cf < 4; ++cf) acc[rt][cf] = z;
    for (int kt = 0; kt < 8; ++kt) {
      short8 a[4], b[4];
#pragma unroll
      for (int rt = 0; rt < 4; ++rt) a[rt] = lds_afrag64(sh, 512, rt, kt, lane);
#pragma unroll
      for (int cf = 0; cf < 4; ++cf)
        b[cf] = ldg_bfrag(W0f, 32, (wv << 2) + cf, (s << 3) + kt, lane);
#pragma unroll
      for (int rt = 0; rt < 4; ++rt)
#pragma unroll
        for (int cf = 0; cf < 4; ++cf)
          acc[rt][cf] = __builtin_amdgcn_mfma_f32_16x16x32_bf16(a[rt], b[cf], acc[rt][cf], 0, 0, 0);
    }
#pragma unroll
    for (int rt = 0; rt < 4; ++rt)
#pragma unroll
      for (int cf = 0; cf < 4; ++cf) {
        int col = (wv << 6) + (cf << 4) + (lane & 15);
#pragma unroll
        for (int i = 0; i < 4; ++i) {
          int row = rt * 16 + ((lane >> 4) << 2) + i;
          int ga = r0 + row;
          if (ga < n_atoms) p[((size_t)ga * 4 + s) * 512 + col] = f2bf(acc[rt][cf][i]);
        }
      }
  }
}

struct P2 {
  const int* idxs;
  const short* p;
  const short *W1, *W2, *W3, *Wt0, *Wt1, *Wc0;
  const float *bs0, *bs1, *bs2, *bs3, *bt0, *bt1, *bt2, *bc0, *bc1;
  const float *Wt2, *Wc1;
  float* out;
  int n_tors;
};

// ================= fused4: BM=32, 16 waves, 2 blocks/CU =================
// wave wv owns cols wv*32 .. wv*32+31  (cf 0..1); rows: rt 0..1 (all 32)

// dual-chain MFMA: shared B; accf = bias + sA@W, accr = bias + sB@W
__device__ __forceinline__ void mfma_dual(const char* sA, const char* sB,
                                          const short* __restrict__ W,
                                          const float* __restrict__ bias,
                                          f32x4 (&accf)[2][2], f32x4 (&accr)[2][2],
                                          int wv, int lane) {
  float b0 = bias[(wv << 5) + (lane & 15)];
  float b1 = bias[(wv << 5) + 16 + (lane & 15)];
#pragma unroll
  for (int rt = 0; rt < 2; ++rt) {
    accf[rt][0] = (f32x4){b0, b0, b0, b0};
    accf[rt][1] = (f32x4){b1, b1, b1, b1};
    accr[rt][0] = (f32x4){b0, b0, b0, b0};
    accr[rt][1] = (f32x4){b1, b1, b1, b1};
  }
  short8 bC[2], bN[2];
#pragma unroll
  for (int cf = 0; cf < 2; ++cf) bC[cf] = ldg_bfrag(W, 16, (wv << 1) + cf, 0, lane);
#pragma unroll 1
  for (int kt = 0; kt < 16; ++kt) {
#pragma unroll
    for (int cf = 0; cf < 2; ++cf)
      bN[cf] = ldg_bfrag(W, 16, (wv << 1) + cf, (kt + 1) & 15, lane);
#pragma unroll
    for (int rt = 0; rt < 2; ++rt) {
      short8 af = lds_a32(sA, rt, kt, lane);
      short8 ar = lds_a32(sB, rt, kt, lane);
#pragma unroll
      for (int cf = 0; cf < 2; ++cf) {
        accf[rt][cf] = __builtin_amdgcn_mfma_f32_16x16x32_bf16(af, bC[cf], accf[rt][cf], 0, 0, 0);
        accr[rt][cf] = __builtin_amdgcn_mfma_f32_16x16x32_bf16(ar, bC[cf], accr[rt][cf], 0, 0, 0);
      }
    }
#pragma unroll
    for (int cf = 0; cf < 2; ++cf) bC[cf] = bN[cf];
  }
}

// dual-B MFMA: one A stream (sym), two weight streams -> accA (Wt0), accB (Wc0)
__device__ __forceinline__ void mfma_dualB(const char* sA,
                                           const short* __restrict__ Wa,
                                           const short* __restrict__ Wb,
                                           const float* __restrict__ ba,
                                           const float* __restrict__ bb,
                                           f32x4 (&accA)[2][2], f32x4 (&accB)[2][2],
                                           int wv, int lane) {
  float a0 = ba[(wv << 5) + (lane & 15)];
  float a1 = ba[(wv << 5) + 16 + (lane & 15)];
  float c0 = bb[(wv << 5) + (lane & 15)];
  float c1 = bb[(wv << 5) + 16 + (lane & 15)];
#pragma unroll
  for (int rt = 0; rt < 2; ++rt) {
    accA[rt][0] = (f32x4){a0, a0, a0, a0};
    accA[rt][1] = (f32x4){a1, a1, a1, a1};
    accB[rt][0] = (f32x4){c0, c0, c0, c0};
    accB[rt][1] = (f32x4){c1, c1, c1, c1};
  }
#pragma unroll 1
  for (int kt = 0; kt < 16; ++kt) {
    short8 bA[2], bB[2];
#pragma unroll
    for (int cf = 0; cf < 2; ++cf) {
      bA[cf] = ldg_bfrag(Wa, 16, (wv << 1) + cf, kt, lane);
      bB[cf] = ldg_bfrag(Wb, 16, (wv << 1) + cf, kt, lane);
    }
#pragma unroll
    for (int rt = 0; rt < 2; ++rt) {
      short8 a = lds_a32(sA, rt, kt, lane);
#pragma unroll
      for (int cf = 0; cf < 2; ++cf) {
        accA[rt][cf] = __builtin_amdgcn_mfma_f32_16x16x32_bf16(a, bA[cf], accA[rt][cf], 0, 0, 0);
        accB[rt][cf] = __builtin_amdgcn_mfma_f32_16x16x32_bf16(a, bB[cf], accB[rt][cf], 0, 0, 0);
      }
    }
  }
}

// single-chain MFMA
__device__ __forceinline__ void mfma_single(const char* src,
                                            const short* __restrict__ W,
                                            const float* __restrict__ bias,
                                            f32x4 (&acc)[2][2], int wv, int lane) {
  float b0 = bias[(wv << 5) + (lane & 15)];
  float b1 = bias[(wv << 5) + 16 + (lane & 15)];
#pragma unroll
  for (int rt = 0; rt < 2; ++rt) {
    acc[rt][0] = (f32x4){b0, b0, b0, b0};
    acc[rt][1] = (f32x4){b1, b1, b1, b1};
  }
  short8 bC[2], bN[2];
#pragma unroll
  for (int cf = 0; cf < 2; ++cf) bC[cf] = ldg_bfrag(W, 16, (wv << 1) + cf, 0, lane);
#pragma unroll 1
  for (int kt = 0; kt < 16; ++kt) {
#pragma unroll
    for (int cf = 0; cf < 2; ++cf)
      bN[cf] = ldg_bfrag(W, 16, (wv << 1) + cf, (kt + 1) & 15, lane);
#pragma unroll
    for (int rt = 0; rt < 2; ++rt) {
      short8 a = lds_a32(src, rt, kt, lane);
#pragma unroll
      for (int cf = 0; cf < 2; ++cf)
        acc[rt][cf] = __builtin_amdgcn_mfma_f32_16x16x32_bf16(a, bC[cf], acc[rt][cf], 0, 0, 0);
    }
#pragma unroll
    for (int cf = 0; cf < 2; ++cf) bC[cf] = bN[cf];
  }
}

__global__ __launch_bounds__(NT4, 8) void fused4(P2 p) {
  __shared__ char sA[BM4 * 1024];
  __shared__ char sB[BM4 * 1024];
  __shared__ int sIdx[BM4 * 4];
  __shared__ float sSmall[BM4 * 12];
  const int tid = threadIdx.x;
  const int lane = tid & 63;
  const int wv = tid >> 6;             // 0..15
  const int r0 = blockIdx.x * BM4;

  if (tid < BM4 * 4) {
    int grow = r0 + (tid >> 2);
    sIdx[tid] = (grow < p.n_tors) ? p.idxs[(size_t)grow * 4 + (tid & 3)] : 0;
  }
  __syncthreads();

  // ---- G: layer0 via gathered per-atom partials -> sA (fwd), sB (rev) ----
#pragma unroll 1
  for (int i = tid; i < BM4 * 64; i += NT4) {
    int row = i >> 6, c0 = (i & 63) << 3;
    float sf[8], sr[8];
#pragma unroll
    for (int e = 0; e < 8; ++e) { sf[e] = p.bs0[c0 + e]; sr[e] = sf[e]; }
#pragma unroll
    for (int j = 0; j < 4; ++j) {
      int a = sIdx[row * 4 + j];
      short8 vf = *(const short8*)(p.p + ((size_t)a * 4 + j) * 512 + c0);
      short8 vr = *(const short8*)(p.p + ((size_t)a * 4 + (3 - j)) * 512 + c0);
#pragma unroll
      for (int e = 0; e < 8; ++e) { sf[e] += bf2f(vf[e]); sr[e] += bf2f(vr[e]); }
    }
    short8 of, orv;
#pragma unroll
    for (int e = 0; e < 8; ++e) { of[e] = f2bf(elu_f(sf[e])); orv[e] = f2bf(elu_f(sr[e])); }
    int off = swz(row, c0 * 2);
    *(short8*)(sA + off) = of;
    *(short8*)(sB + off) = orv;
  }
  __syncthreads();

  f32x4 accA[2][2], accB[2][2];

  // ---- 3 dual residual layers (shared B), in-place; last writes sym->sA ----
  const short* Ws[3] = {p.W1, p.W2, p.W3};
  const float* bs[3] = {p.bs1, p.bs2, p.bs3};
#pragma unroll 1
  for (int L = 0; L < 3; ++L) {
    mfma_dual(sA, sB, Ws[L], bs[L], accA, accB, wv, lane);
    __syncthreads();
#pragma unroll
    for (int rt = 0; rt < 2; ++rt)
#pragma unroll
      for (int cf = 0; cf < 2; ++cf) {
        int col = (wv << 5) + (cf << 4) + (lane & 15);
#pragma unroll
        for (int i = 0; i < 4; ++i) {
          int row = rt * 16 + ((lane >> 4) << 2) + i;
          int off = swz(row, col * 2);
          short* pf = (short*)(sA + off);
          short* pr = (short*)(sB + off);
          float nf = bf2f(*pf) + elu_f(accA[rt][cf][i]);
          float nr = bf2f(*pr) + elu_f(accB[rt][cf][i]);
          if (L == 2) {
            *pf = f2bf(nf + nr);
          } else {
            *pf = f2bf(nf);
            *pr = f2bf(nr);
          }
        }
      }
    __syncthreads();
  }

  // ---- heads: t0 (Wt0) and c (Wc0) from sym (sA), one A stream ----
  mfma_dualB(sA, p.Wt0, p.Wc0, p.bt0, p.bc0, accA, accB, wv, lane);
  __syncthreads();
#pragma unroll
  for (int rt = 0; rt < 2; ++rt)
#pragma unroll
    for (int cf = 0; cf < 2; ++cf) {
      int col = (wv << 5) + (cf << 4) + (lane & 15);
#pragma unroll
      for (int i = 0; i < 4; ++i) {
        int row = rt * 16 + ((lane >> 4) << 2) + i;
        int off = swz(row, col * 2);
        float s = bf2f(*(short*)(sA + off));
        *(short*)(sB + off) = f2bf(s + elu_f(accA[rt][cf][i]));  // t0
        *(short*)(sA + off) = f2bf(s + elu_f(accB[rt][cf][i]));  // c
      }
    }
  __syncthreads();

  // ---- t1 = t0 + elu(t0@Wt1+bt1), in-place in sB ----
  mfma_single(sB, p.Wt1, p.bt1, accA, wv, lane);
  __syncthreads();
#pragma unroll
  for (int rt = 0; rt < 2; ++rt)
#pragma unroll
    for (int cf = 0; cf < 2; ++cf) {
      int col = (wv << 5) + (cf << 4) + (lane & 15);
#pragma unroll
      for (int i = 0; i < 4; ++i) {
        int row = rt * 16 + ((lane >> 4) << 2) + i;
        int off = swz(row, col * 2);
        short* pt = (short*)(sB + off);
        *pt = f2bf(bf2f(*pt) + elu_f(accA[rt][cf][i]));
      }
    }
  __syncthreads();

  // ---- proj: coeffs from t1 (sB), score from c (sA) ----
  if (tid < BM4 * 12) {
    int row = tid / 12, jj = tid - row * 12;
    int j = (jj < 6) ? jj : jj - 6;
    const char* src = (jj < 6) ? sB : sA;
    const float* W = (jj < 6) ? p.Wt2 : p.Wc1;
    float acc = (jj < 6) ? p.bt2[j] : p.bc1[j];
#pragma unroll 1
    for (int c0 = 0; c0 < 512; c0 += 8) {
      short8 v = *(const short8*)(src + swz(row, c0 * 2));
#pragma unroll
      for (int e = 0; e < 8; ++e) acc += bf2f(v[e]) * W[(c0 + e) * 6 + j];
    }
    sSmall[row * 12 + jj] = acc;
  }
  __syncthreads();
  if (tid < BM4 * 6) {
    int row = tid / 6, j = tid - row * 6;
    int grow = r0 + row;
    if (grow < p.n_tors) {
      float score = sSmall[row * 12 + 6 + j];
      float coeff = sSmall[row * 12 + j];
      p.out[(size_t)grow * 6 + j] = score;
      p.out[(size_t)p.n_tors * 6 + (size_t)grow * 6 + j] =
          coeff * 0.001f * (1.0f / (1.0f + __expf(-score)));
    }
  }
}

// ================= LEGACY PATH (fallback if ws too small) =================

struct Params {
  const float* h;
  const int* idxs;
  const short *W0f, *W0r, *W1, *W2, *W3, *Wt0, *Wt1, *Wc0;
  const float *bs0, *bs1, *bs2, *bs3, *bt0, *bt1, *bt2, *bc0, *bc1;
  const float *Wt2, *Wc1;
  float* out;
  int n_tors;
};

__device__ __forceinline__ void layer_dual(char* hf, char* hr,
                                           const short* __restrict__ W,
                                           const float* __restrict__ bias,
                                           int wv, int lane) {
  f32x4 accf[4][4], accr[4][4];
  const f32x4 z = {0.f, 0.f, 0.f, 0.f};
#pragma unroll
  for (int rt = 0; rt < 4; ++rt)
#pragma unroll
    for (int cf = 0; cf < 4; ++cf) { accf[rt][cf] = z; accr[rt][cf] = z; }
  for (int kt = 0; kt < 16; ++kt) {
    short8 af[4], ar[4], b[4];
#pragma unroll
    for (int rt = 0; rt < 4; ++rt) {
      af[rt] = lds_afrag64(hf, 1024, rt, kt, lane);
      ar[rt] = lds_afrag64(hr, 1024, rt, kt, lane);
    }
#pragma unroll
    for (int cf = 0; cf < 4; ++cf) b[cf] = ldg_bfrag(W, 16, (wv << 2) + cf, kt, lane);
#pragma unroll
    for (int rt = 0; rt < 4; ++rt)
#pragma unroll
      for (int cf = 0; cf < 4; ++cf) {
        accf[rt][cf] = __builtin_amdgcn_mfma_f32_16x16x32_bf16(af[rt], b[cf], accf[rt][cf], 0, 0, 0);
        accr[rt][cf] = __builtin_amdgcn_mfma_f32_16x16x32_bf16(ar[rt], b[cf], accr[rt][cf], 0, 0, 0);
      }
  }
  float bcol[4];
#pragma unroll
  for (int cf = 0; cf < 4; ++cf) bcol[cf] = bias[(wv << 6) + (cf << 4) + (lane & 15)];
  __syncthreads();
#pragma unroll
  for (int rt = 0; rt < 4; ++rt)
#pragma unroll
    for (int cf = 0; cf < 4; ++cf) {
      int col = (wv << 6) + (cf << 4) + (lane & 15);
#pragma unroll
      for (int i = 0; i < 4; ++i) {
        int row = rt * 16 + ((lane >> 4) << 2) + i;
        size_t off = (size_t)row * 1024 + ((col * 2) ^ ((row & 7) << 4));
        short* pf = (short*)(hf + off);
        short* pr = (short*)(hr + off);
        *pf = f2bf(bf2f(*pf) + elu_f(accf[rt][cf][i] + bcol[cf]));
        *pr = f2bf(bf2f(*pr) + elu_f(accr[rt][cf][i] + bcol[cf]));
      }
    }
  __syncthreads();
}

__device__ __forceinline__ void layer_single(const char* in,
                                             const short* __restrict__ W,
                                             const float* __restrict__ bias,
                                             const char* res, char* out,
                                             int wv, int lane) {
  f32x4 acc[4][4];
  const f32x4 z = {0.f, 0.f, 0.f, 0.f};
#pragma unroll
  for (int rt = 0; rt < 4; ++rt)
#pragma unroll
    for (int cf = 0; cf < 4; ++cf) acc[rt][cf] = z;
  for (int kt = 0; kt < 16; ++kt) {
    short8 a[4], b[4];
#pragma unroll
    for (int rt = 0; rt < 4; ++rt) a[rt] = lds_afrag64(in, 1024, rt, kt, lane);
#pragma unroll
    for (int cf = 0; cf < 4; ++cf) b[cf] = ldg_bfrag(W, 16, (wv << 2) + cf, kt, lane);
#pragma unroll
    for (int rt = 0; rt < 4; ++rt)
#pragma unroll
      for (int cf = 0; cf < 4; ++cf)
        acc[rt][cf] = __builtin_amdgcn_mfma_f32_16x16x32_bf16(a[rt], b[cf], acc[rt][cf], 0, 0, 0);
  }
  float bcol[4];
#pragma unroll
  for (int cf = 0; cf < 4; ++cf) bcol[cf] = bias[(wv << 6) + (cf << 4) + (lane & 15)];
  __syncthreads();
#pragma unroll
  for (int rt = 0; rt < 4; ++rt)
#pragma unroll
    for (int cf = 0; cf < 4; ++cf) {
      int col = (wv << 6) + (cf << 4) + (lane & 15);
#pragma unroll
      for (int i = 0; i < 4; ++i) {
        int row = rt * 16 + ((lane >> 4) << 2) + i;
        size_t off = (size_t)row * 1024 + ((col * 2) ^ ((row & 7) << 4));
        float v = elu_f(acc[rt][cf][i] + bcol[cf]) + bf2f(*(const short*)(res + off));
        *(short*)(out + off) = f2bf(v);
      }
    }
  __syncthreads();
}

__global__ __launch_bounds__(NTHREADS) void fused(Params p) {
  __shared__ char smem[BM * 2048];
  __shared__ float sSmall[BM * 12];
  char* sA = smem;
  char* sB = smem + BM * 1024;
  const int tid = threadIdx.x;
  const int lane = tid & 63;
  const int wv = tid >> 6;
  const int r0 = blockIdx.x * BM;

  for (int c = tid; c < BM * 128; c += NTHREADS) {
    int row = c >> 7;
    int col0 = (c & 127) << 3;
    int grow = r0 + row;
    short8 o;
    if (grow < p.n_tors) {
      int f = col0 >> 8;
      int cin = col0 & 255;
      int a = p.idxs[(size_t)grow * 4 + f];
      const float4* s4 = (const float4*)(p.h + (size_t)a * 256 + cin);
      float4 v0 = s4[0], v1 = s4[1];
      o[0] = f2bf(v0.x); o[1] = f2bf(v0.y); o[2] = f2bf(v0.z); o[3] = f2bf(v0.w);
      o[4] = f2bf(v1.x); o[5] = f2bf(v1.y); o[6] = f2bf(v1.z); o[7] = f2bf(v1.w);
    } else {
#pragma unroll
      for (int e = 0; e < 8; ++e) o[e] = 0;
    }
    *(short8*)(smem + (size_t)row * 2048 + ((col0 * 2) ^ ((row & 7) << 4))) = o;
  }
  __syncthreads();

  {
    f32x4 accf[4][4], accr[4][4];
    const f32x4 z = {0.f, 0.f, 0.f, 0.f};
#pragma unroll
    for (int rt = 0; rt < 4; ++rt)
#pragma unroll
      for (int cf = 0; cf < 4; ++cf) { accf[rt][cf] = z; accr[rt][cf] = z; }
    for (int kt = 0; kt < 32; ++kt) {
      short8 a[4], bfw[4], brw[4];
#pragma unroll
      for (int rt = 0; rt < 4; ++rt) a[rt] = lds_afrag64(smem, 2048, rt, kt, lane);
#pragma unroll
      for (int cf = 0; cf < 4; ++cf) {
        bfw[cf] = ldg_bfrag(p.W0f, 32, (wv << 2) + cf, kt, lane);
        brw[cf] = ldg_bfrag(p.W0r, 32, (wv << 2) + cf, kt, lane);
      }
#pragma unroll
      for (int rt = 0; rt < 4; ++rt)
#pragma unroll
        for (int cf = 0; cf < 4; ++cf) {
          accf[rt][cf] = __builtin_amdgcn_mfma_f32_16x16x32_bf16(a[rt], bfw[cf], accf[rt][cf], 0, 0, 0);
          accr[rt][cf] = __builtin_amdgcn_mfma_f32_16x16x32_bf16(a[rt], brw[cf], accr[rt][cf], 0, 0, 0);
        }
    }
    float bcol[4];
#pragma unroll
    for (int cf = 0; cf < 4; ++cf) bcol[cf] = p.bs0[(wv << 6) + (cf << 4) + (lane & 15)];
    __syncthreads();
#pragma unroll
    for (int rt = 0; rt < 4; ++rt)
#pragma unroll
      for (int cf = 0; cf < 4; ++cf) {
        int col = (wv << 6) + (cf << 4) + (lane & 15);
#pragma unroll
        for (int i = 0; i < 4; ++i) {
          int row = rt * 16 + ((lane >> 4) << 2) + i;
          size_t off = (size_t)row * 1024 + ((col * 2) ^ ((row & 7) << 4));
          *(short*)(sA + off) = f2bf(elu_f(accf[rt][cf][i] + bcol[cf]));
          *(short*)(sB + off) = f2bf(elu_f(accr[rt][cf][i] + bcol[cf]));
        }
      }
    __syncthreads();
  }

  layer_dual(sA, sB, p.W1, p.bs1, wv, lane);
  layer_dual(sA, sB, p.W2, p.bs2, wv, lane);
  layer_dual(sA, sB, p.W3, p.bs3, wv, lane);

  for (int c = tid; c < BM * 64; c += NTHREADS) {
    int row = c >> 6;
    int col0 = (c & 63) << 3;
    size_t off = (size_t)row * 1024 + ((col0 * 2) ^ ((row & 7) << 4));
    short8 xa = *(short8*)(sA + off);
    short8 xb = *(short8*)(sB + off);
    short8 o;
#pragma unroll
    for (int e = 0; e < 8; ++e) o[e] = f2bf(bf2f(xa[e]) + bf2f(xb[e]));
    *(short8*)(sA + off) = o;
  }
  __syncthreads();

  layer_single(sA, p.Wt0, p.bt0, sA, sB, wv, lane);
  layer_single(sB, p.Wt1, p.bt1, sB, sB, wv, lane);
  layer_single(sA, p.Wc0, p.bc0, sA, sA, wv, lane);

  for (int idx = tid; idx < BM * 12; idx += NTHREADS) {
    int row = idx / 12, jj = idx - row * 12;
    int j = (jj < 6) ? jj : jj - 6;
    const char* src = (jj < 6) ? sB : sA;
    const float* W = (jj < 6) ? p.Wt2 : p.Wc1;
    float acc = (jj < 6) ? p.bt2[j] : p.bc1[j];
    for (int c0 = 0; c0 < 512; c0 += 8) {
      short8 v = *(const short8*)(src + (size_t)row * 1024 + ((c0 * 2) ^ ((row & 7) << 4)));
#pragma unroll
      for (int e = 0; e < 8; ++e) acc += bf2f(v[e]) * W[(c0 + e) * 6 + j];
    }
    sSmall[row * 12 + jj] = acc;
  }
  __syncthreads();
  for (int idx = tid; idx < BM * 6; idx += NTHREADS) {
    int row = idx / 6, j = idx - row * 6;
    int grow = r0 + row;
    if (grow < p.n_tors) {
      float score = sSmall[row * 12 + 6 + j];
      float coeff = sSmall[row * 12 + j];
      p.out[(size_t)grow * 6 + j] = score;
      p.out[(size_t)p.n_tors * 6 + (size_t)grow * 6 + j] =
          coeff * 0.001f * (1.0f / (1.0f + __expf(-score)));
    }
  }
}

// ================= LAUNCH =================

extern "C" void kernel_launch(void* const* d_in, const int* in_sizes, int n_in,
                              void* d_out, int out_size, void* d_ws, size_t ws_size,
                              hipStream_t stream) {
  const float* h   = (const float*)d_in[0];
  const int* idxs  = (const int*)d_in[1];
  const float* Ws0 = (const float*)d_in[2];
  const float* bs0 = (const float*)d_in[3];
  const float* Ws1 = (const float*)d_in[4];
  const float* bs1 = (const float*)d_in[5];
  const float* Ws2 = (const float*)d_in[6];
  const float* bs2 = (const float*)d_in[7];
  const float* Ws3 = (const float*)d_in[8];
  const float* bs3 = (const float*)d_in[9];
  const float* Wt0 = (const float*)d_in[10];
  const float* bt0 = (const float*)d_in[11];
  const float* Wt1 = (const float*)d_in[12];
  const float* bt1 = (const float*)d_in[13];
  const float* Wt2 = (const float*)d_in[14];
  const float* bt2 = (const float*)d_in[15];
  const float* Wc0 = (const float*)d_in[16];
  const float* bc0 = (const float*)d_in[17];
  const float* Wc1 = (const float*)d_in[18];
  const float* bc1 = (const float*)d_in[19];
  int n_tors = in_sizes[1] / 4;
  int n_atoms = in_sizes[0] / 256;

  auto pk = [&](const float* s, short* dmem, int K, int N, int rev) {
    int tiles = (N >> 4) * (K >> 5);
    pack_w<<<dim3((tiles + 3) / 4), dim3(256), 0, stream>>>(s, dmem, K, N, rev);
  };

  size_t pElems = (size_t)n_atoms * 4 * 512;
  size_t needNew = (pElems + 524288 + 6 * 262144) * sizeof(short);

  if (ws_size >= needNew) {
    short* ws = (short*)d_ws;
    short* pT  = ws;
    short* W0f = ws + pElems;
    short* W1  = W0f + 524288;
    short* W2  = W1 + 262144;
    short* W3  = W2 + 262144;
    short* Wt0c = W3 + 262144;
    short* Wt1c = Wt0c + 262144;
    short* Wc0c = Wt1c + 262144;

    pk(Ws0, W0f, 1024, 512, 0);
    pk(Ws1, W1, 512, 512, 0);
    pk(Ws2, W2, 512, 512, 0);
    pk(Ws3, W3, 512, 512, 0);
    pk(Wt0, Wt0c, 512, 512, 0);
    pk(Wt1, Wt1c, 512, 512, 0);
    pk(Wc0, Wc0c, 512, 512, 0);

    atom_pre<<<dim3((n_atoms + BM - 1) / BM), dim3(NTHREADS), 0, stream>>>(h, W0f, pT, n_atoms);

    P2 p;
    p.idxs = idxs; p.p = pT;
    p.W1 = W1; p.W2 = W2; p.W3 = W3;
    p.Wt0 = Wt0c; p.Wt1 = Wt1c; p.Wc0 = Wc0c;
    p.bs0 = bs0; p.bs1 = bs1; p.bs2 = bs2; p.bs3 = bs3;
    p.bt0 = bt0; p.bt1 = bt1; p.bt2 = bt2; p.bc0 = bc0; p.bc1 = bc1;
    p.Wt2 = Wt2; p.Wc1 = Wc1;
    p.out = (float*)d_out; p.n_tors = n_tors;

    fused4<<<dim3((n_tors + BM4 - 1) / BM4), dim3(NT4), 0, stream>>>(p);
  } else {
    short* ws = (short*)d_ws;
    short* W0f = ws;
    short* W0r = ws + 524288;
    short* W1  = ws + 1048576;
    short* W2  = W1 + 262144;
    short* W3  = W2 + 262144;
    short* Wt0c = W3 + 262144;
    short* Wt1c = Wt0c + 262144;
    short* Wc0c = Wt1c + 262144;

    pk(Ws0, W0f, 1024, 512, 0);
    pk(Ws0, W0r, 1024, 512, 1);
    pk(Ws1, W1, 512, 512, 0);
    pk(Ws2, W2, 512, 512, 0);
    pk(Ws3, W3, 512, 512, 0);
    pk(Wt0, Wt0c, 512, 512, 0);
    pk(Wt1, Wt1c, 512, 512, 0);
    pk(Wc0, Wc0c, 512, 512, 0);

    Params p;
    p.h = h; p.idxs = idxs;
    p.W0f = W0f; p.W0r = W0r; p.W1 = W1; p.W2 = W2; p.W3 = W3;
    p.Wt0 = Wt0c; p.Wt1 = Wt1c; p.Wc0 = Wc0c;
    p.bs0 = bs0; p.bs1 = bs1; p.bs2 = bs2; p.bs3 = bs3;
    p.bt0 = bt0; p.bt1 = bt1; p.bt2 = bt2; p.bc0 = bc0; p.bc1 = bc1;
    p.Wt2 = Wt2; p.Wc1 = Wc1;
    p.out = (float*)d_out; p.n_tors = n_tors;

    fused<<<dim3((n_tors + BM - 1) / BM), dim3(NTHREADS), 0, stream>>>(p);
  }
}